// Round 14
// baseline (166.689 us; speedup 1.0000x reference)
//
#include <hip/hip_runtime.h>
#include <hip/hip_bf16.h>

#define HH 8
#define NN 2048
#define DD 64

typedef __attribute__((ext_vector_type(8))) short bf16x8;
typedef __attribute__((ext_vector_type(4))) float f32x4;
typedef __attribute__((ext_vector_type(8))) unsigned short u16x8;
typedef unsigned short ushort_t;

static __device__ __forceinline__ unsigned short f2bf(float x) {
    union { float f; unsigned u; } un; un.f = x;
    unsigned r = un.u + 0x7FFFu + ((un.u >> 16) & 1u);  // RNE
    return (unsigned short)(r >> 16);
}
static __device__ __forceinline__ unsigned short f2bf_t(float x) {  // truncate (1 VALU)
    union { float f; unsigned u; } un; un.f = x;
    return (unsigned short)(un.u >> 16);
}
static __device__ __forceinline__ float bf2f(unsigned short u) {
    union { unsigned u; float f; } un; un.u = ((unsigned)u) << 16;
    return un.f;
}

// ---------------- ws layout (bytes) ----------------
#define OFF_Q  0u
#define OFF_K  2097152u
#define OFF_VT 4194304u
#define OFF_R  6291456u
#define OFF_P  6815744u          // partials: [256 streams][2 subs][32][68] f32
#define OFF_F  11272192u         // flags: [256] int (zeroed by pre_kernel each call)
#define WS_NEED 11273216u

// ---------------- merged pre-pass: f32->bf16 (q,k,rpe) + V transpose + flag zero ----------------
#define NQ4 262144   // 8*2048*64/4
#define NR4 65520    // 4095*64/4
#define CVT_BLOCKS 2305
__global__ void pre_kernel(const float* __restrict__ q, const float* __restrict__ k,
                           const float* __restrict__ r, const float* __restrict__ v,
                           ushort_t* __restrict__ ws) {
    __shared__ __align__(16) ushort_t T[64][72];
    // zero the cross-block handoff flags (ws is re-poisoned to 0xAA before every call)
    if (blockIdx.x == CVT_BLOCKS && threadIdx.x < 256)
        ((int*)((char*)ws + OFF_F))[threadIdx.x] = 0;
    if (blockIdx.x < CVT_BLOCKS) {
        int idx = blockIdx.x * 256 + threadIdx.x;
        const float* src; ushort_t* dst; int off;
        if (idx < NQ4) { src = q; dst = (ushort_t*)((char*)ws + OFF_Q); off = idx; }
        else if (idx < 2 * NQ4) { src = k; dst = (ushort_t*)((char*)ws + OFF_K); off = idx - NQ4; }
        else if (idx < 2 * NQ4 + NR4) { src = r; dst = (ushort_t*)((char*)ws + OFF_R); off = idx - 2 * NQ4; }
        else return;
        float4 f = *(const float4*)&src[4 * (size_t)off];
        ushort4 u; u.x = f2bf(f.x); u.y = f2bf(f.y); u.z = f2bf(f.z); u.w = f2bf(f.w);
        *(ushort4*)&dst[4 * (size_t)off] = u;
    } else {
        ushort_t* vt = (ushort_t*)((char*)ws + OFF_VT);
        const int bb = blockIdx.x - CVT_BLOCKS;          // 0..255
        const int h = bb >> 5;
        const int n0 = (bb & 31) * 64;
        const int tid = threadIdx.x;
        const float* vh = v + (size_t)h * NN * DD;
        #pragma unroll
        for (int p = 0; p < 4; ++p) {
            int c = tid + 256 * p; int rr = c >> 4, dc = (c & 15) << 2;
            float4 f = *(const float4*)&vh[(size_t)(n0 + rr) * DD + dc];
            T[dc + 0][rr] = f2bf(f.x); T[dc + 1][rr] = f2bf(f.y);
            T[dc + 2][rr] = f2bf(f.z); T[dc + 3][rr] = f2bf(f.w);
        }
        __syncthreads();
        #pragma unroll
        for (int p = 0; p < 2; ++p) {
            int c = tid + 256 * p; int d = c >> 3, nn = (c & 7) << 3;
            *(u16x8*)&vt[((size_t)h * 64 + d) * NN + n0 + nn] = *(const u16x8*)&T[d][nn];
        }
    }
}

// ---------------- main kernel (R9 + fused tile-A combine via atomic handoff) ----------------
// 512 blocks: (stream s in [0,256), sub sb). Pair p: tiles A=63-p (njtA>=17), B=p (njtB<=16);
// sb0 = A[0,17), sb1 = A[17,njtA) + all of B. Wave w: rt=w&1 (16-row strip), ch=w>>1
// (32-col j-half); Ts/Ws wave-private. Double-buffered staging, 1 barrier/iter.
// Tile-A epilogue: both subs write their partial + threadfence + atomicAdd(flag);
// the SECOND arriver sums its LDS Epi with the partner's ws partial and writes out
// (device-scope per G16; no spin -> no deadlock; both subs ALWAYS reach the atomic,
// even when a sub's A j-range is empty). combine_kernel eliminated.
__global__ __launch_bounds__(256, 2)
void fastmax_main(const ushort_t* __restrict__ wsb, float* __restrict__ outg,
                  float* __restrict__ wsPart, int* __restrict__ flags)
{
    __shared__ __align__(16) ushort_t Ks[2][64][72];
    __shared__ __align__(16) ushort_t Bs[2][96][72];
    __shared__ __align__(16) ushort_t Vts[2][64][72];
    __shared__ __align__(16) unsigned char U[12800]; // union: Ts[4][48][20]u16 (7680) + Ws[4][16][40]u16 (5120) | Epi[32][68]f32 (8704)
    __shared__ int flagOld;
    float* Epi = (float*)U;

    const ushort_t* qb  = (const ushort_t*)((const char*)wsb + OFF_Q);
    const ushort_t* kb  = (const ushort_t*)((const char*)wsb + OFF_K);
    const ushort_t* vtb = (const ushort_t*)((const char*)wsb + OFF_VT);
    const ushort_t* rb_ = (const ushort_t*)((const char*)wsb + OFF_R);

    const int tid = threadIdx.x;
    const int w   = tid >> 6;
    const int l   = tid & 63;
    const int lq  = l >> 4;
    const int ln  = l & 15;
    const int rt  = w & 1;
    const int ch  = w >> 1;

    ushort_t* tsW = (ushort_t*)(U + w * 1920);           // Ts[w]: [48][20] u16
    ushort_t* wsW = (ushort_t*)(U + 7680 + w * 1280);    // Ws[w]: [16][40] u16

    const int sb     = blockIdx.x & 1;
    const int stream = blockIdx.x >> 1;
    const int head   = stream & 7;
    const int p      = stream >> 3;          // 0..31
    const int tileA  = 63 - p;
    const int njtA   = (tileA >> 1) + 1;     // 17..32
    const int tileB  = p;
    const int njtB   = (tileB >> 1) + 1;     // 1..16

    const ushort_t* qh  = qb  + (size_t)head * NN * DD;
    const ushort_t* kh  = kb  + (size_t)head * NN * DD;
    const ushort_t* vth = vtb + (size_t)head * DD * NN;
    float*          oh  = outg + (size_t)head * NN * DD;

    const int sw = 16 * rt - 32 * ch + 32;   // wave's band-window start (0..48)

    // staging prefetch registers (7 x u16x8)
    u16x8 rk0, rk1, rbA, rbB, rbC, rv0, rv1;
    const int c0r = tid >> 3,         c0d = (tid & 7) << 3;
    const int c1r = (tid + 256) >> 3, c1d = ((tid + 256) & 7) << 3;
    const int c2r = (tid + 512) >> 3, c2d = ((tid + 512) & 7) << 3;

    #pragma unroll 1
    for (int tsel = 0; tsel < 2; ++tsel) {
        if (tsel == 1 && sb == 0) break;     // uniform per block
        const int tile = tsel ? tileB : tileA;
        const int jlo  = tsel ? 0 : (sb ? 17 : 0);
        const int jhi  = tsel ? njtB : (sb ? njtA : 17);
        const int i0   = tile * 32;

        bf16x8 qf0 = *(const bf16x8*)&qh[(size_t)(i0 + 16 * rt + ln) * DD +  0 + 8 * lq];
        bf16x8 qf1 = *(const bf16x8*)&qh[(size_t)(i0 + 16 * rt + ln) * DD + 32 + 8 * lq];

        f32x4 acc0 = {0,0,0,0}, acc1 = {0,0,0,0}, acc2 = {0,0,0,0}, acc3 = {0,0,0,0};
        float denv0 = 0.f, denv1 = 0.f, denv2 = 0.f, denv3 = 0.f;

        // ---- prologue prefetch (iter jlo)
        {
            const int j0 = jlo * 64;
            const int relbase = i0 - j0 + 1984;
            rk0 = *(const u16x8*)&kh[(size_t)(j0 + c0r) * DD + c0d];
            rk1 = *(const u16x8*)&kh[(size_t)(j0 + c1r) * DD + c1d];
            int r0 = relbase + c0r; if (r0 > 4094) r0 = 4094;
            int r1 = relbase + c1r; if (r1 > 4094) r1 = 4094;
            int r2 = relbase + c2r; if (r2 > 4094) r2 = 4094;
            rbA = *(const u16x8*)&rb_[(size_t)r0 * DD + c0d];
            rbB = *(const u16x8*)&rb_[(size_t)r1 * DD + c1d];
            rbC = *(const u16x8*)&rb_[(size_t)r2 * DD + c2d];
            rv0 = *(const u16x8*)&vth[(size_t)c0r * NN + j0 + c0d];
            rv1 = *(const u16x8*)&vth[(size_t)c1r * NN + j0 + c1d];
        }

        int buf = 0;
        for (int jt = jlo; jt < jhi; ++jt) {
            const int j0 = jt * 64;

            // ---- commit prefetched regs -> LDS[buf]
            *(u16x8*)&Ks[buf][c0r][c0d] = rk0;
            *(u16x8*)&Ks[buf][c1r][c1d] = rk1;
            *(u16x8*)&Bs[buf][c0r][c0d] = rbA;
            *(u16x8*)&Bs[buf][c1r][c1d] = rbB;
            *(u16x8*)&Bs[buf][c2r][c2d] = rbC;
            *(u16x8*)&Vts[buf][c0r][c0d] = rv0;
            *(u16x8*)&Vts[buf][c1r][c1d] = rv1;

            // ---- issue next iter's loads (in flight across compute)
            if (jt + 1 < jhi) {
                const int jn = j0 + 64;
                const int relbase = i0 - jn + 1984;
                rk0 = *(const u16x8*)&kh[(size_t)(jn + c0r) * DD + c0d];
                rk1 = *(const u16x8*)&kh[(size_t)(jn + c1r) * DD + c1d];
                int r0 = relbase + c0r; if (r0 > 4094) r0 = 4094;
                int r1 = relbase + c1r; if (r1 > 4094) r1 = 4094;
                int r2 = relbase + c2r; if (r2 > 4094) r2 = 4094;
                rbA = *(const u16x8*)&rb_[(size_t)r0 * DD + c0d];
                rbB = *(const u16x8*)&rb_[(size_t)r1 * DD + c1d];
                rbC = *(const u16x8*)&rb_[(size_t)r2 * DD + c2d];
                rv0 = *(const u16x8*)&vth[(size_t)c0r * NN + jn + c0d];
                rv1 = *(const u16x8*)&vth[(size_t)c1r * NN + jn + c1d];
            }

            __syncthreads();   // LDS[buf] complete; prior iter's LDS[buf^1] reads already done

            // ---- S = Q K^T over wave quadrant
            f32x4 s0 = {0,0,0,0}, s1 = {0,0,0,0};
            {
                bf16x8 b00 = *(const bf16x8*)&Ks[buf][32 * ch      + ln][ 0 + 8 * lq];
                bf16x8 b01 = *(const bf16x8*)&Ks[buf][32 * ch      + ln][32 + 8 * lq];
                bf16x8 b10 = *(const bf16x8*)&Ks[buf][32 * ch + 16 + ln][ 0 + 8 * lq];
                bf16x8 b11 = *(const bf16x8*)&Ks[buf][32 * ch + 16 + ln][32 + 8 * lq];
                s0 = __builtin_amdgcn_mfma_f32_16x16x32_bf16(qf0, b00, s0, 0, 0, 0);
                s0 = __builtin_amdgcn_mfma_f32_16x16x32_bf16(qf1, b01, s0, 0, 0, 0);
                s1 = __builtin_amdgcn_mfma_f32_16x16x32_bf16(qf0, b10, s1, 0, 0, 0);
                s1 = __builtin_amdgcn_mfma_f32_16x16x32_bf16(qf1, b11, s1, 0, 0, 0);
            }

            // ---- T = Q band^T, wave-private window [sw, sw+48): 3 b-tiles
            // Ts col-major [bw][rp] stride 20, one b64 (ushort4) write per tile (4 rows packed)
            #pragma unroll
            for (int bt = 0; bt < 3; ++bt) {
                f32x4 t = {0,0,0,0};
                bf16x8 b0 = *(const bf16x8*)&Bs[buf][sw + 16 * bt + ln][ 0 + 8 * lq];
                bf16x8 b1 = *(const bf16x8*)&Bs[buf][sw + 16 * bt + ln][32 + 8 * lq];
                t = __builtin_amdgcn_mfma_f32_16x16x32_bf16(qf0, b0, t, 0, 0, 0);
                t = __builtin_amdgcn_mfma_f32_16x16x32_bf16(qf1, b1, t, 0, 0, 0);
                ushort4 pk;
                pk.x = f2bf_t(t[0]); pk.y = f2bf_t(t[1]);
                pk.z = f2bf_t(t[2]); pk.w = f2bf_t(t[3]);
                *(ushort4*)&tsW[(16 * bt + ln) * 20 + 4 * lq] = pk;   // 8B-aligned: 40*ln'+8*lq
            }

            // ---- gather + Taylor weight + mask -> Ws (trunc bf16) + denominator
            #pragma unroll
            for (int ct = 0; ct < 2; ++ct) {
                f32x4 sv = ct ? s1 : s0;
                #pragma unroll
                for (int e = 0; e < 4; ++e) {
                    int rp = 4 * lq + e;                      // row within strip
                    int cp = 16 * ct + ln;                    // col within quadrant
                    int bw = rp - cp + 31;                    // in [0,47]
                    float s = sv[e] + bf2f(tsW[bw * 20 + rp]);
                    float wv = 1.0f + s + 0.5f * s * s;
                    if (j0 + 32 * ch + cp > i0 + 16 * rt + rp) wv = 0.0f;
                    union { float f; unsigned u; } uw; uw.f = wv;
                    wsW[rp * 40 + cp] = (ushort_t)(uw.u >> 16);  // trunc bf16
                    uw.u &= 0xffff0000u;                         // exact bf16 value MFMA sees
                    if (e == 0) denv0 += uw.f; else if (e == 1) denv1 += uw.f;
                    else if (e == 2) denv2 += uw.f; else denv3 += uw.f;
                }
            }

            // ---- PV += W * V^T over wave's j-half (K=32)
            {
                bf16x8 af = *(const bf16x8*)&wsW[ln * 40 + 8 * lq];  // wave-private RAW
                bf16x8 b;
                b = *(const bf16x8*)&Vts[buf][ 0 + ln][32 * ch + 8 * lq];
                acc0 = __builtin_amdgcn_mfma_f32_16x16x32_bf16(af, b, acc0, 0, 0, 0);
                b = *(const bf16x8*)&Vts[buf][16 + ln][32 * ch + 8 * lq];
                acc1 = __builtin_amdgcn_mfma_f32_16x16x32_bf16(af, b, acc1, 0, 0, 0);
                b = *(const bf16x8*)&Vts[buf][32 + ln][32 * ch + 8 * lq];
                acc2 = __builtin_amdgcn_mfma_f32_16x16x32_bf16(af, b, acc2, 0, 0, 0);
                b = *(const bf16x8*)&Vts[buf][48 + ln][32 * ch + 8 * lq];
                acc3 = __builtin_amdgcn_mfma_f32_16x16x32_bf16(af, b, acc3, 0, 0, 0);
            }
            buf ^= 1;
        }

        // ---- reduce denominator across the wave's 16 n-lanes
        #pragma unroll
        for (int off = 1; off <= 8; off <<= 1) {
            denv0 += __shfl_xor(denv0, off);
            denv1 += __shfl_xor(denv1, off);
            denv2 += __shfl_xor(denv2, off);
            denv3 += __shfl_xor(denv3, off);
        }

        // ---- epilogue: combine ch halves in Epi (union; ordered by barriers)
        __syncthreads();
        if (ch == 0) {
            #pragma unroll
            for (int e = 0; e < 4; ++e) {
                int r = 16 * rt + 4 * lq + e;
                Epi[r * 68 +  0 + ln] = acc0[e];
                Epi[r * 68 + 16 + ln] = acc1[e];
                Epi[r * 68 + 32 + ln] = acc2[e];
                Epi[r * 68 + 48 + ln] = acc3[e];
            }
            if (ln == 0) {
                Epi[(16 * rt + 4 * lq + 0) * 68 + 64] = denv0;
                Epi[(16 * rt + 4 * lq + 1) * 68 + 64] = denv1;
                Epi[(16 * rt + 4 * lq + 2) * 68 + 64] = denv2;
                Epi[(16 * rt + 4 * lq + 3) * 68 + 64] = denv3;
            }
        }
        __syncthreads();
        if (ch == 1) {
            #pragma unroll
            for (int e = 0; e < 4; ++e) {
                int r = 16 * rt + 4 * lq + e;
                Epi[r * 68 +  0 + ln] += acc0[e];
                Epi[r * 68 + 16 + ln] += acc1[e];
                Epi[r * 68 + 32 + ln] += acc2[e];
                Epi[r * 68 + 48 + ln] += acc3[e];
            }
            if (ln == 0) {
                Epi[(16 * rt + 4 * lq + 0) * 68 + 64] += denv0;
                Epi[(16 * rt + 4 * lq + 1) * 68 + 64] += denv1;
                Epi[(16 * rt + 4 * lq + 2) * 68 + 64] += denv2;
                Epi[(16 * rt + 4 * lq + 3) * 68 + 64] += denv3;
            }
        }
        __syncthreads();
        if (tsel == 0) {
            // write my tile-A partial, then device-scope handoff: second arriver combines
            float* dst = wsPart + ((size_t)(head * 32 + p) * 2 + sb) * (32 * 68);
            for (int idx = tid; idx < 32 * 68; idx += 256) dst[idx] = Epi[idx];
            __threadfence();                 // release my stores (agent scope)
            __syncthreads();                 // all threads' stores drained + fenced
            if (tid == 0) flagOld = atomicAdd(&flags[head * 32 + p], 1);
            __syncthreads();
            if (flagOld == 1) {              // I'm second: partner's partial is visible
                __threadfence();             // acquire
                const float* pp = wsPart + ((size_t)(head * 32 + p) * 2 + (sb ^ 1)) * (32 * 68);
                #pragma unroll
                for (int e2 = 0; e2 < 8; ++e2) {
                    int idx = tid + 256 * e2;
                    int r = idx >> 6, d = idx & 63;
                    float num = Epi[r * 68 + d] + pp[r * 68 + d];
                    float den = Epi[r * 68 + 64] + pp[r * 68 + 64];
                    oh[(size_t)(i0 + r) * DD + d] = num / den;
                }
            }
        } else {
            #pragma unroll
            for (int e2 = 0; e2 < 8; ++e2) {
                int idx = tid + 256 * e2;
                int r = idx >> 6, d = idx & 63;
                oh[(size_t)(i0 + r) * DD + d] = Epi[r * 68 + d] / Epi[r * 68 + 64];
            }
        }
        // next segment: Ts/Ws writes happen only after its loop's first barrier -> Epi safe
    }
}

// ---------------- fallback (round-2 proven kernel, no ws) ----------------
__global__ __launch_bounds__(256, 2)
void fastmax_fallback(const float* __restrict__ qg0, const float* __restrict__ kg0,
                      const float* __restrict__ vg0, const float* __restrict__ rg,
                      float* __restrict__ outg)
{
    __shared__ __align__(16) ushort_t Qs[32][72];
    __shared__ __align__(16) ushort_t Ks2[64][72];
    __shared__ __align__(16) ushort_t Bs2[96][72];
    __shared__ __align__(16) ushort_t Vts2[96][72];
    __shared__ __align__(16) float    Tsf[32][97];
    __shared__ __align__(16) ushort_t Wsf[32][72];
    __shared__ float denomLds[32];

    const int tid = threadIdx.x;
    const int w = tid >> 6, l = tid & 63, lq = l >> 4, ln = l & 15;
    const int head = blockIdx.x & 7, ib = blockIdx.x >> 3;
    const int it = 63 - ib, i0 = it * 32, njt = (it >> 1) + 1;
    const float* qg = qg0 + (size_t)head * NN * DD;
    const float* kg = kg0 + (size_t)head * NN * DD;
    const float* vg = vg0 + (size_t)head * NN * DD;
    float* og = outg + (size_t)head * NN * DD;
    {
        #pragma unroll
        for (int p = 0; p < 2; ++p) {
            int c = tid + 256 * p; int r = c >> 4, dc = (c & 15) << 2;
            float4 f = *(const float4*)&qg[(size_t)(i0 + r) * DD + dc];
            ushort4 u; u.x = f2bf(f.x); u.y = f2bf(f.y); u.z = f2bf(f.z); u.w = f2bf(f.w);
            *(ushort4*)&Qs[r][dc] = u;
        }
        for (int idx = tid; idx < 32 * 72; idx += 256) {
            int rr = idx / 72, cc = idx - rr * 72;
            Vts2[64 + rr][cc] = (rr == 0) ? (ushort_t)0x3F80 : (ushort_t)0;
        }
    }
    f32x4 a0 = {0,0,0,0}, a1 = {0,0,0,0}, a2 = {0,0,0,0};
    const int pr = w & 1, rt = w & 1, cp = w >> 1;
    for (int jt = 0; jt < njt; ++jt) {
        const int j0 = jt * 64;
        __syncthreads();
        #pragma unroll
        for (int p = 0; p < 4; ++p) {
            int c = tid + 256 * p; int r = c >> 4, dc = (c & 15) << 2;
            float4 f = *(const float4*)&kg[(size_t)(j0 + r) * DD + dc];
            ushort4 u; u.x = f2bf(f.x); u.y = f2bf(f.y); u.z = f2bf(f.z); u.w = f2bf(f.w);
            *(ushort4*)&Ks2[r][dc] = u;
        }
        const int relbase = i0 - j0 + 1984;
        #pragma unroll
        for (int p = 0; p < 6; ++p) {
            int c = tid + 256 * p; int r = c >> 4, dc = (c & 15) << 2;
            int row = relbase + r; if (row > 4094) row = 4094;
            float4 f = *(const float4*)&rg[(size_t)row * DD + dc];
            ushort4 u; u.x = f2bf(f.x); u.y = f2bf(f.y); u.z = f2bf(f.z); u.w = f2bf(f.w);
            *(ushort4*)&Bs2[r][dc] = u;
        }
        #pragma unroll
        for (int p = 0; p < 4; ++p) {
            int c = tid + 256 * p; int r = c >> 4, dc = (c & 15) << 2;
            float4 f = *(const float4*)&vg[(size_t)(j0 + r) * DD + dc];
            Vts2[dc + 0][r] = f2bf(f.x); Vts2[dc + 1][r] = f2bf(f.y);
            Vts2[dc + 2][r] = f2bf(f.z); Vts2[dc + 3][r] = f2bf(f.w);
        }
        __syncthreads();
        f32x4 s0 = {0,0,0,0}, s1 = {0,0,0,0};
        #pragma unroll
        for (int ks = 0; ks < 2; ++ks) {
            bf16x8 a = *(const bf16x8*)&Qs[16 * rt + ln][32 * ks + 8 * lq];
            bf16x8 b0 = *(const bf16x8*)&Ks2[32 * cp + ln][32 * ks + 8 * lq];
            bf16x8 b1 = *(const bf16x8*)&Ks2[32 * cp + 16 + ln][32 * ks + 8 * lq];
            s0 = __builtin_amdgcn_mfma_f32_16x16x32_bf16(a, b0, s0, 0, 0, 0);
            s1 = __builtin_amdgcn_mfma_f32_16x16x32_bf16(a, b1, s1, 0, 0, 0);
        }
        #pragma unroll
        for (int kk = 0; kk < 3; ++kk) {
            int bt = (w >> 1) + 2 * kk;
            f32x4 t = {0,0,0,0};
            #pragma unroll
            for (int ks = 0; ks < 2; ++ks) {
                bf16x8 a = *(const bf16x8*)&Qs[16 * rt + ln][32 * ks + 8 * lq];
                bf16x8 b = *(const bf16x8*)&Bs2[16 * bt + ln][32 * ks + 8 * lq];
                t = __builtin_amdgcn_mfma_f32_16x16x32_bf16(a, b, t, 0, 0, 0);
            }
            #pragma unroll
            for (int e = 0; e < 4; ++e) Tsf[16 * rt + 4 * lq + e][16 * bt + ln] = t[e];
        }
        __syncthreads();
        #pragma unroll
        for (int ct2 = 0; ct2 < 2; ++ct2) {
            f32x4 sv = ct2 ? s1 : s0;
            int c_loc = 32 * cp + 16 * ct2 + ln, j = j0 + c_loc;
            #pragma unroll
            for (int e = 0; e < 4; ++e) {
                int r_loc = 16 * rt + 4 * lq + e, i = i0 + r_loc;
                float s = sv[e] + Tsf[r_loc][r_loc - c_loc + 63];
                float wv = 1.0f + s + 0.5f * s * s;
                if (j > i) wv = 0.0f;
                Wsf[r_loc][c_loc] = f2bf(wv);
            }
        }
        __syncthreads();
        {
            bf16x8 af0 = *(const bf16x8*)&Wsf[16 * pr + ln][ 0 + 8 * lq];
            bf16x8 af1 = *(const bf16x8*)&Wsf[16 * pr + ln][32 + 8 * lq];
            int pn0 = w >> 1; bf16x8 b;
            b = *(const bf16x8*)&Vts2[16 * (pn0 + 0) + ln][ 0 + 8 * lq];
            a0 = __builtin_amdgcn_mfma_f32_16x16x32_bf16(af0, b, a0, 0, 0, 0);
            b = *(const bf16x8*)&Vts2[16 * (pn0 + 0) + ln][32 + 8 * lq];
            a0 = __builtin_amdgcn_mfma_f32_16x16x32_bf16(af1, b, a0, 0, 0, 0);
            b = *(const bf16x8*)&Vts2[16 * (pn0 + 2) + ln][ 0 + 8 * lq];
            a1 = __builtin_amdgcn_mfma_f32_16x16x32_bf16(af0, b, a1, 0, 0, 0);
            b = *(const bf16x8*)&Vts2[16 * (pn0 + 2) + ln][32 + 8 * lq];
            a1 = __builtin_amdgcn_mfma_f32_16x16x32_bf16(af1, b, a1, 0, 0, 0);
            b = *(const bf16x8*)&Vts2[16 * (pn0 + 4) + ln][ 0 + 8 * lq];
            a2 = __builtin_amdgcn_mfma_f32_16x16x32_bf16(af0, b, a2, 0, 0, 0);
            b = *(const bf16x8*)&Vts2[16 * (pn0 + 4) + ln][32 + 8 * lq];
            a2 = __builtin_amdgcn_mfma_f32_16x16x32_bf16(af1, b, a2, 0, 0, 0);
        }
    }
    if (w < 2 && ln == 0) {
        #pragma unroll
        for (int e = 0; e < 4; ++e) denomLds[16 * pr + 4 * lq + e] = a2[e];
    }
    __syncthreads();
    #pragma unroll
    for (int k = 0; k < 2; ++k) {
        int pn = (w >> 1) + 2 * k;
        f32x4 acc = k ? a1 : a0;
        #pragma unroll
        for (int e = 0; e < 4; ++e) {
            int r_loc = 16 * pr + 4 * lq + e;
            og[(size_t)(i0 + r_loc) * DD + 16 * pn + ln] = acc[e] / denomLds[r_loc];
        }
    }
}

extern "C" void kernel_launch(void* const* d_in, const int* in_sizes, int n_in,
                              void* d_out, int out_size, void* d_ws, size_t ws_size,
                              hipStream_t stream) {
    const float* q   = (const float*)d_in[0];
    const float* k   = (const float*)d_in[1];
    const float* v   = (const float*)d_in[2];
    const float* rpe = (const float*)d_in[3];
    float* out = (float*)d_out;

    if (ws_size >= WS_NEED) {
        ushort_t* wsb = (ushort_t*)d_ws;
        float* wsPart = (float*)((char*)d_ws + OFF_P);
        int* flags = (int*)((char*)d_ws + OFF_F);
        hipLaunchKernelGGL(pre_kernel, dim3(CVT_BLOCKS + 256), dim3(256), 0, stream,
                           q, k, rpe, v, wsb);
        hipLaunchKernelGGL(fastmax_main, dim3(512), dim3(256), 0, stream,
                           wsb, out, wsPart, flags);
    } else {
        hipLaunchKernelGGL(fastmax_fallback, dim3(512), dim3(256), 0, stream,
                           q, k, v, rpe, out);
    }
}

// Round 15
// 102.505 us; speedup vs baseline: 1.6262x; 1.6262x over previous
//
#include <hip/hip_runtime.h>
#include <hip/hip_bf16.h>

#define HH 8
#define NN 2048
#define DD 64

typedef __attribute__((ext_vector_type(8))) short bf16x8;
typedef __attribute__((ext_vector_type(4))) float f32x4;
typedef __attribute__((ext_vector_type(8))) unsigned short u16x8;
typedef unsigned short ushort_t;

static __device__ __forceinline__ unsigned short f2bf(float x) {
    union { float f; unsigned u; } un; un.f = x;
    unsigned r = un.u + 0x7FFFu + ((un.u >> 16) & 1u);  // RNE
    return (unsigned short)(r >> 16);
}
static __device__ __forceinline__ unsigned short f2bf_t(float x) {  // truncate (1 VALU)
    union { float f; unsigned u; } un; un.f = x;
    return (unsigned short)(un.u >> 16);
}
static __device__ __forceinline__ float bf2f(unsigned short u) {
    union { unsigned u; float f; } un; un.u = ((unsigned)u) << 16;
    return un.f;
}

// ---------------- ws layout (bytes) ----------------
#define OFF_Q  0u
#define OFF_K  2097152u
#define OFF_VT 4194304u
#define OFF_R  6291456u
#define OFF_P  6815744u          // partials: [256 streams][2 subs][32][68] f32
#define WS_NEED 11272192u

// ---------------- merged pre-pass: f32->bf16 (q,k,rpe) + V transpose (R4-proven) ----------------
#define NQ4 262144   // 8*2048*64/4
#define NR4 65520    // 4095*64/4
#define CVT_BLOCKS 2305
__global__ void pre_kernel(const float* __restrict__ q, const float* __restrict__ k,
                           const float* __restrict__ r, const float* __restrict__ v,
                           ushort_t* __restrict__ ws) {
    __shared__ __align__(16) ushort_t T[64][72];
    if (blockIdx.x < CVT_BLOCKS) {
        int idx = blockIdx.x * 256 + threadIdx.x;
        const float* src; ushort_t* dst; int off;
        if (idx < NQ4) { src = q; dst = (ushort_t*)((char*)ws + OFF_Q); off = idx; }
        else if (idx < 2 * NQ4) { src = k; dst = (ushort_t*)((char*)ws + OFF_K); off = idx - NQ4; }
        else if (idx < 2 * NQ4 + NR4) { src = r; dst = (ushort_t*)((char*)ws + OFF_R); off = idx - 2 * NQ4; }
        else return;
        float4 f = *(const float4*)&src[4 * (size_t)off];
        ushort4 u; u.x = f2bf(f.x); u.y = f2bf(f.y); u.z = f2bf(f.z); u.w = f2bf(f.w);
        *(ushort4*)&dst[4 * (size_t)off] = u;
    } else {
        ushort_t* vt = (ushort_t*)((char*)ws + OFF_VT);
        const int bb = blockIdx.x - CVT_BLOCKS;          // 0..255
        const int h = bb >> 5;
        const int n0 = (bb & 31) * 64;
        const int tid = threadIdx.x;
        const float* vh = v + (size_t)h * NN * DD;
        #pragma unroll
        for (int p = 0; p < 4; ++p) {
            int c = tid + 256 * p; int rr = c >> 4, dc = (c & 15) << 2;
            float4 f = *(const float4*)&vh[(size_t)(n0 + rr) * DD + dc];
            T[dc + 0][rr] = f2bf(f.x); T[dc + 1][rr] = f2bf(f.y);
            T[dc + 2][rr] = f2bf(f.z); T[dc + 3][rr] = f2bf(f.w);
        }
        __syncthreads();
        #pragma unroll
        for (int p = 0; p < 2; ++p) {
            int c = tid + 256 * p; int d = c >> 3, nn = (c & 7) << 3;
            *(u16x8*)&vt[((size_t)h * 64 + d) * NN + n0 + nn] = *(const u16x8*)&T[d][nn];
        }
    }
}

// ---------------- main kernel (R8 + trunc-bf16 + Ts col-major b64 packing) ----------------
// 512 blocks: (stream s in [0,256), sub sb). Pair p: tiles A=63-p (njtA>=17), B=p (njtB<=16);
// sb0 = A[0,17), sb1 = A[17,njtA) + all of B. Wave w: rt=w&1 (16-row strip), ch=w>>1
// (32-col j-half); Ts/Ws wave-private. Double-buffered staging, 1 barrier/iter.
// Ts col-major [bw 0..47][rp 0..15] bf16 stride 20: one ushort4 (b64) write packs the
// 4 C-elements of a quad (same col, rows 4lq+e). Trunc bf16 everywhere in the hot loop.
__global__ __launch_bounds__(256, 2)
void fastmax_main(const ushort_t* __restrict__ wsb, float* __restrict__ outg,
                  float* __restrict__ wsPart)
{
    __shared__ __align__(16) ushort_t Ks[2][64][72];
    __shared__ __align__(16) ushort_t Bs[2][96][72];
    __shared__ __align__(16) ushort_t Vts[2][64][72];
    __shared__ __align__(16) unsigned char U[12800]; // union: Ts[4][48][20]u16 (7680) + Ws[4][16][40]u16 (5120) | Epi[32][68]f32 (8704)
    float* Epi = (float*)U;

    const ushort_t* qb  = (const ushort_t*)((const char*)wsb + OFF_Q);
    const ushort_t* kb  = (const ushort_t*)((const char*)wsb + OFF_K);
    const ushort_t* vtb = (const ushort_t*)((const char*)wsb + OFF_VT);
    const ushort_t* rb_ = (const ushort_t*)((const char*)wsb + OFF_R);

    const int tid = threadIdx.x;
    const int w   = tid >> 6;
    const int l   = tid & 63;
    const int lq  = l >> 4;
    const int ln  = l & 15;
    const int rt  = w & 1;
    const int ch  = w >> 1;

    ushort_t* tsW = (ushort_t*)(U + w * 1920);           // Ts[w]: [48][20] u16
    ushort_t* wsW = (ushort_t*)(U + 7680 + w * 1280);    // Ws[w]: [16][40] u16

    const int sb     = blockIdx.x & 1;
    const int stream = blockIdx.x >> 1;
    const int head   = stream & 7;
    const int p      = stream >> 3;          // 0..31
    const int tileA  = 63 - p;
    const int njtA   = (tileA >> 1) + 1;     // 17..32
    const int tileB  = p;
    const int njtB   = (tileB >> 1) + 1;     // 1..16

    const ushort_t* qh  = qb  + (size_t)head * NN * DD;
    const ushort_t* kh  = kb  + (size_t)head * NN * DD;
    const ushort_t* vth = vtb + (size_t)head * DD * NN;
    float*          oh  = outg + (size_t)head * NN * DD;

    const int sw = 16 * rt - 32 * ch + 32;   // wave's band-window start (0..48)

    // staging prefetch registers (7 x u16x8)
    u16x8 rk0, rk1, rbA, rbB, rbC, rv0, rv1;
    const int c0r = tid >> 3,         c0d = (tid & 7) << 3;
    const int c1r = (tid + 256) >> 3, c1d = ((tid + 256) & 7) << 3;
    const int c2r = (tid + 512) >> 3, c2d = ((tid + 512) & 7) << 3;

    #pragma unroll 1
    for (int tsel = 0; tsel < 2; ++tsel) {
        if (tsel == 1 && sb == 0) break;     // uniform per block
        const int tile = tsel ? tileB : tileA;
        const int jlo  = tsel ? 0 : (sb ? 17 : 0);
        const int jhi  = tsel ? njtB : (sb ? njtA : 17);
        const int i0   = tile * 32;

        bf16x8 qf0 = *(const bf16x8*)&qh[(size_t)(i0 + 16 * rt + ln) * DD +  0 + 8 * lq];
        bf16x8 qf1 = *(const bf16x8*)&qh[(size_t)(i0 + 16 * rt + ln) * DD + 32 + 8 * lq];

        f32x4 acc0 = {0,0,0,0}, acc1 = {0,0,0,0}, acc2 = {0,0,0,0}, acc3 = {0,0,0,0};
        float denv0 = 0.f, denv1 = 0.f, denv2 = 0.f, denv3 = 0.f;

        // ---- prologue prefetch (iter jlo)
        {
            const int j0 = jlo * 64;
            const int relbase = i0 - j0 + 1984;
            rk0 = *(const u16x8*)&kh[(size_t)(j0 + c0r) * DD + c0d];
            rk1 = *(const u16x8*)&kh[(size_t)(j0 + c1r) * DD + c1d];
            int r0 = relbase + c0r; if (r0 > 4094) r0 = 4094;
            int r1 = relbase + c1r; if (r1 > 4094) r1 = 4094;
            int r2 = relbase + c2r; if (r2 > 4094) r2 = 4094;
            rbA = *(const u16x8*)&rb_[(size_t)r0 * DD + c0d];
            rbB = *(const u16x8*)&rb_[(size_t)r1 * DD + c1d];
            rbC = *(const u16x8*)&rb_[(size_t)r2 * DD + c2d];
            rv0 = *(const u16x8*)&vth[(size_t)c0r * NN + j0 + c0d];
            rv1 = *(const u16x8*)&vth[(size_t)c1r * NN + j0 + c1d];
        }

        int buf = 0;
        for (int jt = jlo; jt < jhi; ++jt) {
            const int j0 = jt * 64;

            // ---- commit prefetched regs -> LDS[buf]
            *(u16x8*)&Ks[buf][c0r][c0d] = rk0;
            *(u16x8*)&Ks[buf][c1r][c1d] = rk1;
            *(u16x8*)&Bs[buf][c0r][c0d] = rbA;
            *(u16x8*)&Bs[buf][c1r][c1d] = rbB;
            *(u16x8*)&Bs[buf][c2r][c2d] = rbC;
            *(u16x8*)&Vts[buf][c0r][c0d] = rv0;
            *(u16x8*)&Vts[buf][c1r][c1d] = rv1;

            // ---- issue next iter's loads (in flight across compute)
            if (jt + 1 < jhi) {
                const int jn = j0 + 64;
                const int relbase = i0 - jn + 1984;
                rk0 = *(const u16x8*)&kh[(size_t)(jn + c0r) * DD + c0d];
                rk1 = *(const u16x8*)&kh[(size_t)(jn + c1r) * DD + c1d];
                int r0 = relbase + c0r; if (r0 > 4094) r0 = 4094;
                int r1 = relbase + c1r; if (r1 > 4094) r1 = 4094;
                int r2 = relbase + c2r; if (r2 > 4094) r2 = 4094;
                rbA = *(const u16x8*)&rb_[(size_t)r0 * DD + c0d];
                rbB = *(const u16x8*)&rb_[(size_t)r1 * DD + c1d];
                rbC = *(const u16x8*)&rb_[(size_t)r2 * DD + c2d];
                rv0 = *(const u16x8*)&vth[(size_t)c0r * NN + jn + c0d];
                rv1 = *(const u16x8*)&vth[(size_t)c1r * NN + jn + c1d];
            }

            __syncthreads();   // LDS[buf] complete; prior iter's LDS[buf^1] reads already done

            // ---- S = Q K^T over wave quadrant
            f32x4 s0 = {0,0,0,0}, s1 = {0,0,0,0};
            {
                bf16x8 b00 = *(const bf16x8*)&Ks[buf][32 * ch      + ln][ 0 + 8 * lq];
                bf16x8 b01 = *(const bf16x8*)&Ks[buf][32 * ch      + ln][32 + 8 * lq];
                bf16x8 b10 = *(const bf16x8*)&Ks[buf][32 * ch + 16 + ln][ 0 + 8 * lq];
                bf16x8 b11 = *(const bf16x8*)&Ks[buf][32 * ch + 16 + ln][32 + 8 * lq];
                s0 = __builtin_amdgcn_mfma_f32_16x16x32_bf16(qf0, b00, s0, 0, 0, 0);
                s0 = __builtin_amdgcn_mfma_f32_16x16x32_bf16(qf1, b01, s0, 0, 0, 0);
                s1 = __builtin_amdgcn_mfma_f32_16x16x32_bf16(qf0, b10, s1, 0, 0, 0);
                s1 = __builtin_amdgcn_mfma_f32_16x16x32_bf16(qf1, b11, s1, 0, 0, 0);
            }

            // ---- T = Q band^T, wave-private window [sw, sw+48): 3 b-tiles
            // Ts col-major [bw][rp] stride 20, one b64 (ushort4) write per tile (4 rows packed)
            #pragma unroll
            for (int bt = 0; bt < 3; ++bt) {
                f32x4 t = {0,0,0,0};
                bf16x8 b0 = *(const bf16x8*)&Bs[buf][sw + 16 * bt + ln][ 0 + 8 * lq];
                bf16x8 b1 = *(const bf16x8*)&Bs[buf][sw + 16 * bt + ln][32 + 8 * lq];
                t = __builtin_amdgcn_mfma_f32_16x16x32_bf16(qf0, b0, t, 0, 0, 0);
                t = __builtin_amdgcn_mfma_f32_16x16x32_bf16(qf1, b1, t, 0, 0, 0);
                ushort4 pk;
                pk.x = f2bf_t(t[0]); pk.y = f2bf_t(t[1]);
                pk.z = f2bf_t(t[2]); pk.w = f2bf_t(t[3]);
                *(ushort4*)&tsW[(16 * bt + ln) * 20 + 4 * lq] = pk;   // 8B-aligned: 40*ln'+8*lq
            }

            // ---- gather + Taylor weight + mask -> Ws (trunc bf16) + denominator
            #pragma unroll
            for (int ct = 0; ct < 2; ++ct) {
                f32x4 sv = ct ? s1 : s0;
                #pragma unroll
                for (int e = 0; e < 4; ++e) {
                    int rp = 4 * lq + e;                      // row within strip
                    int cp = 16 * ct + ln;                    // col within quadrant
                    int bw = rp - cp + 31;                    // in [0,47]
                    float s = sv[e] + bf2f(tsW[bw * 20 + rp]);
                    float wv = 1.0f + s + 0.5f * s * s;
                    if (j0 + 32 * ch + cp > i0 + 16 * rt + rp) wv = 0.0f;
                    union { float f; unsigned u; } uw; uw.f = wv;
                    wsW[rp * 40 + cp] = (ushort_t)(uw.u >> 16);  // trunc bf16
                    uw.u &= 0xffff0000u;                         // exact bf16 value MFMA sees
                    if (e == 0) denv0 += uw.f; else if (e == 1) denv1 += uw.f;
                    else if (e == 2) denv2 += uw.f; else denv3 += uw.f;
                }
            }

            // ---- PV += W * V^T over wave's j-half (K=32)
            {
                bf16x8 af = *(const bf16x8*)&wsW[ln * 40 + 8 * lq];  // wave-private RAW
                bf16x8 b;
                b = *(const bf16x8*)&Vts[buf][ 0 + ln][32 * ch + 8 * lq];
                acc0 = __builtin_amdgcn_mfma_f32_16x16x32_bf16(af, b, acc0, 0, 0, 0);
                b = *(const bf16x8*)&Vts[buf][16 + ln][32 * ch + 8 * lq];
                acc1 = __builtin_amdgcn_mfma_f32_16x16x32_bf16(af, b, acc1, 0, 0, 0);
                b = *(const bf16x8*)&Vts[buf][32 + ln][32 * ch + 8 * lq];
                acc2 = __builtin_amdgcn_mfma_f32_16x16x32_bf16(af, b, acc2, 0, 0, 0);
                b = *(const bf16x8*)&Vts[buf][48 + ln][32 * ch + 8 * lq];
                acc3 = __builtin_amdgcn_mfma_f32_16x16x32_bf16(af, b, acc3, 0, 0, 0);
            }
            buf ^= 1;
        }

        // ---- reduce denominator across the wave's 16 n-lanes
        #pragma unroll
        for (int off = 1; off <= 8; off <<= 1) {
            denv0 += __shfl_xor(denv0, off);
            denv1 += __shfl_xor(denv1, off);
            denv2 += __shfl_xor(denv2, off);
            denv3 += __shfl_xor(denv3, off);
        }

        // ---- epilogue: combine ch halves in Epi (union; ordered by barriers)
        __syncthreads();
        if (ch == 0) {
            #pragma unroll
            for (int e = 0; e < 4; ++e) {
                int r = 16 * rt + 4 * lq + e;
                Epi[r * 68 +  0 + ln] = acc0[e];
                Epi[r * 68 + 16 + ln] = acc1[e];
                Epi[r * 68 + 32 + ln] = acc2[e];
                Epi[r * 68 + 48 + ln] = acc3[e];
            }
            if (ln == 0) {
                Epi[(16 * rt + 4 * lq + 0) * 68 + 64] = denv0;
                Epi[(16 * rt + 4 * lq + 1) * 68 + 64] = denv1;
                Epi[(16 * rt + 4 * lq + 2) * 68 + 64] = denv2;
                Epi[(16 * rt + 4 * lq + 3) * 68 + 64] = denv3;
            }
        }
        __syncthreads();
        if (ch == 1) {
            #pragma unroll
            for (int e = 0; e < 4; ++e) {
                int r = 16 * rt + 4 * lq + e;
                Epi[r * 68 +  0 + ln] += acc0[e];
                Epi[r * 68 + 16 + ln] += acc1[e];
                Epi[r * 68 + 32 + ln] += acc2[e];
                Epi[r * 68 + 48 + ln] += acc3[e];
            }
            if (ln == 0) {
                Epi[(16 * rt + 4 * lq + 0) * 68 + 64] += denv0;
                Epi[(16 * rt + 4 * lq + 1) * 68 + 64] += denv1;
                Epi[(16 * rt + 4 * lq + 2) * 68 + 64] += denv2;
                Epi[(16 * rt + 4 * lq + 3) * 68 + 64] += denv3;
            }
        }
        __syncthreads();
        if (tsel == 0) {
            float* dst = wsPart + ((size_t)(head * 32 + p) * 2 + sb) * (32 * 68);
            for (int idx = tid; idx < 32 * 68; idx += 256) dst[idx] = Epi[idx];
        } else {
            #pragma unroll
            for (int e2 = 0; e2 < 8; ++e2) {
                int idx = tid + 256 * e2;
                int r = idx >> 6, d = idx & 63;
                oh[(size_t)(i0 + r) * DD + d] = Epi[r * 68 + d] / Epi[r * 68 + 64];
            }
        }
        // next segment: Ts/Ws writes happen only after its loop's first barrier -> Epi safe
    }
}

// ---------------- combine: tile A = two partials summed, divide (R3-proven) ----------------
__global__ void combine_kernel(const float* __restrict__ wsPart, float* __restrict__ outg) {
    const int blk = blockIdx.x;              // 0..255 = head*32 + p
    const int head = blk >> 5;
    const int p = blk & 31;
    const int tileA = 63 - p;
    const float* p0 = wsPart + (size_t)blk * 2 * (32 * 68);
    const float* p1 = p0 + 32 * 68;
    float* oh = outg + (size_t)head * NN * DD;
    #pragma unroll
    for (int e2 = 0; e2 < 8; ++e2) {
        int idx = threadIdx.x + 256 * e2;
        int r = idx >> 6, d = idx & 63;
        float num = p0[r * 68 + d] + p1[r * 68 + d];
        float den = p0[r * 68 + 64] + p1[r * 68 + 64];
        oh[(size_t)(tileA * 32 + r) * DD + d] = num / den;
    }
}

// ---------------- fallback (round-2 proven kernel, no ws) ----------------
__global__ __launch_bounds__(256, 2)
void fastmax_fallback(const float* __restrict__ qg0, const float* __restrict__ kg0,
                      const float* __restrict__ vg0, const float* __restrict__ rg,
                      float* __restrict__ outg)
{
    __shared__ __align__(16) ushort_t Qs[32][72];
    __shared__ __align__(16) ushort_t Ks2[64][72];
    __shared__ __align__(16) ushort_t Bs2[96][72];
    __shared__ __align__(16) ushort_t Vts2[96][72];
    __shared__ __align__(16) float    Tsf[32][97];
    __shared__ __align__(16) ushort_t Wsf[32][72];
    __shared__ float denomLds[32];

    const int tid = threadIdx.x;
    const int w = tid >> 6, l = tid & 63, lq = l >> 4, ln = l & 15;
    const int head = blockIdx.x & 7, ib = blockIdx.x >> 3;
    const int it = 63 - ib, i0 = it * 32, njt = (it >> 1) + 1;
    const float* qg = qg0 + (size_t)head * NN * DD;
    const float* kg = kg0 + (size_t)head * NN * DD;
    const float* vg = vg0 + (size_t)head * NN * DD;
    float* og = outg + (size_t)head * NN * DD;
    {
        #pragma unroll
        for (int p = 0; p < 2; ++p) {
            int c = tid + 256 * p; int r = c >> 4, dc = (c & 15) << 2;
            float4 f = *(const float4*)&qg[(size_t)(i0 + r) * DD + dc];
            ushort4 u; u.x = f2bf(f.x); u.y = f2bf(f.y); u.z = f2bf(f.z); u.w = f2bf(f.w);
            *(ushort4*)&Qs[r][dc] = u;
        }
        for (int idx = tid; idx < 32 * 72; idx += 256) {
            int rr = idx / 72, cc = idx - rr * 72;
            Vts2[64 + rr][cc] = (rr == 0) ? (ushort_t)0x3F80 : (ushort_t)0;
        }
    }
    f32x4 a0 = {0,0,0,0}, a1 = {0,0,0,0}, a2 = {0,0,0,0};
    const int pr = w & 1, rt = w & 1, cp = w >> 1;
    for (int jt = 0; jt < njt; ++jt) {
        const int j0 = jt * 64;
        __syncthreads();
        #pragma unroll
        for (int p = 0; p < 4; ++p) {
            int c = tid + 256 * p; int r = c >> 4, dc = (c & 15) << 2;
            float4 f = *(const float4*)&kg[(size_t)(j0 + r) * DD + dc];
            ushort4 u; u.x = f2bf(f.x); u.y = f2bf(f.y); u.z = f2bf(f.z); u.w = f2bf(f.w);
            *(ushort4*)&Ks2[r][dc] = u;
        }
        const int relbase = i0 - j0 + 1984;
        #pragma unroll
        for (int p = 0; p < 6; ++p) {
            int c = tid + 256 * p; int r = c >> 4, dc = (c & 15) << 2;
            int row = relbase + r; if (row > 4094) row = 4094;
            float4 f = *(const float4*)&rg[(size_t)row * DD + dc];
            ushort4 u; u.x = f2bf(f.x); u.y = f2bf(f.y); u.z = f2bf(f.z); u.w = f2bf(f.w);
            *(ushort4*)&Bs2[r][dc] = u;
        }
        #pragma unroll
        for (int p = 0; p < 4; ++p) {
            int c = tid + 256 * p; int r = c >> 4, dc = (c & 15) << 2;
            float4 f = *(const float4*)&vg[(size_t)(j0 + r) * DD + dc];
            Vts2[dc + 0][r] = f2bf(f.x); Vts2[dc + 1][r] = f2bf(f.y);
            Vts2[dc + 2][r] = f2bf(f.z); Vts2[dc + 3][r] = f2bf(f.w);
        }
        __syncthreads();
        f32x4 s0 = {0,0,0,0}, s1 = {0,0,0,0};
        #pragma unroll
        for (int ks = 0; ks < 2; ++ks) {
            bf16x8 a = *(const bf16x8*)&Qs[16 * rt + ln][32 * ks + 8 * lq];
            bf16x8 b0 = *(const bf16x8*)&Ks2[32 * cp + ln][32 * ks + 8 * lq];
            bf16x8 b1 = *(const bf16x8*)&Ks2[32 * cp + 16 + ln][32 * ks + 8 * lq];
            s0 = __builtin_amdgcn_mfma_f32_16x16x32_bf16(a, b0, s0, 0, 0, 0);
            s1 = __builtin_amdgcn_mfma_f32_16x16x32_bf16(a, b1, s1, 0, 0, 0);
        }
        #pragma unroll
        for (int kk = 0; kk < 3; ++kk) {
            int bt = (w >> 1) + 2 * kk;
            f32x4 t = {0,0,0,0};
            #pragma unroll
            for (int ks = 0; ks < 2; ++ks) {
                bf16x8 a = *(const bf16x8*)&Qs[16 * rt + ln][32 * ks + 8 * lq];
                bf16x8 b = *(const bf16x8*)&Bs2[16 * bt + ln][32 * ks + 8 * lq];
                t = __builtin_amdgcn_mfma_f32_16x16x32_bf16(a, b, t, 0, 0, 0);
            }
            #pragma unroll
            for (int e = 0; e < 4; ++e) Tsf[16 * rt + 4 * lq + e][16 * bt + ln] = t[e];
        }
        __syncthreads();
        #pragma unroll
        for (int ct2 = 0; ct2 < 2; ++ct2) {
            f32x4 sv = ct2 ? s1 : s0;
            int c_loc = 32 * cp + 16 * ct2 + ln, j = j0 + c_loc;
            #pragma unroll
            for (int e = 0; e < 4; ++e) {
                int r_loc = 16 * rt + 4 * lq + e, i = i0 + r_loc;
                float s = sv[e] + Tsf[r_loc][r_loc - c_loc + 63];
                float wv = 1.0f + s + 0.5f * s * s;
                if (j > i) wv = 0.0f;
                Wsf[r_loc][c_loc] = f2bf(wv);
            }
        }
        __syncthreads();
        {
            bf16x8 af0 = *(const bf16x8*)&Wsf[16 * pr + ln][ 0 + 8 * lq];
            bf16x8 af1 = *(const bf16x8*)&Wsf[16 * pr + ln][32 + 8 * lq];
            int pn0 = w >> 1; bf16x8 b;
            b = *(const bf16x8*)&Vts2[16 * (pn0 + 0) + ln][ 0 + 8 * lq];
            a0 = __builtin_amdgcn_mfma_f32_16x16x32_bf16(af0, b, a0, 0, 0, 0);
            b = *(const bf16x8*)&Vts2[16 * (pn0 + 0) + ln][32 + 8 * lq];
            a0 = __builtin_amdgcn_mfma_f32_16x16x32_bf16(af1, b, a0, 0, 0, 0);
            b = *(const bf16x8*)&Vts2[16 * (pn0 + 2) + ln][ 0 + 8 * lq];
            a1 = __builtin_amdgcn_mfma_f32_16x16x32_bf16(af0, b, a1, 0, 0, 0);
            b = *(const bf16x8*)&Vts2[16 * (pn0 + 2) + ln][32 + 8 * lq];
            a1 = __builtin_amdgcn_mfma_f32_16x16x32_bf16(af1, b, a1, 0, 0, 0);
            b = *(const bf16x8*)&Vts2[16 * (pn0 + 4) + ln][ 0 + 8 * lq];
            a2 = __builtin_amdgcn_mfma_f32_16x16x32_bf16(af0, b, a2, 0, 0, 0);
            b = *(const bf16x8*)&Vts2[16 * (pn0 + 4) + ln][32 + 8 * lq];
            a2 = __builtin_amdgcn_mfma_f32_16x16x32_bf16(af1, b, a2, 0, 0, 0);
        }
    }
    if (w < 2 && ln == 0) {
        #pragma unroll
        for (int e = 0; e < 4; ++e) denomLds[16 * pr + 4 * lq + e] = a2[e];
    }
    __syncthreads();
    #pragma unroll
    for (int k = 0; k < 2; ++k) {
        int pn = (w >> 1) + 2 * k;
        f32x4 acc = k ? a1 : a0;
        #pragma unroll
        for (int e = 0; e < 4; ++e) {
            int r_loc = 16 * pr + 4 * lq + e;
            og[(size_t)(i0 + r_loc) * DD + 16 * pn + ln] = acc[e] / denomLds[r_loc];
        }
    }
}

extern "C" void kernel_launch(void* const* d_in, const int* in_sizes, int n_in,
                              void* d_out, int out_size, void* d_ws, size_t ws_size,
                              hipStream_t stream) {
    const float* q   = (const float*)d_in[0];
    const float* k   = (const float*)d_in[1];
    const float* v   = (const float*)d_in[2];
    const float* rpe = (const float*)d_in[3];
    float* out = (float*)d_out;

    if (ws_size >= WS_NEED) {
        ushort_t* wsb = (ushort_t*)d_ws;
        float* wsPart = (float*)((char*)d_ws + OFF_P);
        hipLaunchKernelGGL(pre_kernel, dim3(CVT_BLOCKS + 256), dim3(256), 0, stream,
                           q, k, rpe, v, wsb);
        hipLaunchKernelGGL(fastmax_main, dim3(512), dim3(256), 0, stream,
                           wsb, out, wsPart);
        hipLaunchKernelGGL(combine_kernel, dim3(256), dim3(256), 0, stream, wsPart, out);
    } else {
        hipLaunchKernelGGL(fastmax_fallback, dim3(512), dim3(256), 0, stream,
                           q, k, v, rpe, out);
    }
}